// Round 1
// baseline (206.540 us; speedup 1.0000x reference)
//
#include <hip/hip_runtime.h>
#include <hip/hip_bf16.h>

#define Bz 2
#define Tz 8
#define Cz 256
#define Hz 24
#define Wz 24
#define NHz 8
#define HCz 32
#define Gz 16
#define HWz 576
#define Mz 4608
#define Nz 36

// workspace float offsets
#define WS_XC 0
#define WS_Q  2359296
#define WS_POS 4718592
#define WS_XS 4720320
#define WS_K  4738752
#define WS_V  4757184
#define WS_FLAG 4775616

__device__ __forceinline__ float ldg_f(const void* p, int i, int bf) {
  return bf ? __bfloat162float(((const __hip_bfloat16*)p)[i])
            : ((const float*)p)[i];
}

// ---------------- dtype detection ----------------
// If the buffer really holds fp32, the even ushorts are random mantissa bits:
// interpreted as bf16 their exponents are wild. Genuine bf16 N(0,1) data has
// sane exponents everywhere.
__global__ void k_detect(const void* x, int* flagout) {
  int lane = threadIdx.x;
  const unsigned short* u = (const unsigned short*)x;
  int wild = 0;
  for (int i = lane; i < 512; i += 64) {
    unsigned short s = u[i];
    int e = (s >> 7) & 0xFF;
    if (e != 0 && (e < 90 || e > 160)) wild++;
  }
  for (int off = 32; off; off >>= 1) wild += __shfl_down(wild, off);
  if (lane == 0) flagout[0] = (wild > 40) ? 0 : 1;  // 1 => bf16 I/O
}

// ---------------- GEMM: C[r][n] = sum_k A[r][k]*W[n][k] + bias[n] ----------------
// MODE 0: A = x in (B,T,C,H,W) layout (dtype per flag), row r=(bt,hw), k=c
// MODE 1: A = fp32 row-major [r][256]
template<int MODE>
__global__ __launch_bounds__(256) void k_gemm(const void* A, const void* Bw, const void* bias,
                                              float* Cout, const int* flag) {
  const int bf = flag[0];
  __shared__ float As[16][68];
  __shared__ float Bs[16][68];
  int tid = threadIdx.x;
  int tx = tid & 15, ty = tid >> 4;
  int row0 = blockIdx.y * 64;
  int col0 = blockIdx.x * 64;
  float acc[4][4] = {};
  for (int k0 = 0; k0 < 256; k0 += 16) {
    if (MODE == 0) {
      int bt = row0 / 576;
      int hw0 = row0 % 576;
      int r = tid & 63;
      int kkb = tid >> 6;
#pragma unroll
      for (int i = 0; i < 4; i++) {
        int kk = kkb + i * 4;
        As[kk][r] = ldg_f(A, (bt * 256 + k0 + kk) * 576 + hw0 + r, bf);
      }
    } else {
      int kk = tid & 15;
      int rb = tid >> 4;
#pragma unroll
      for (int i = 0; i < 4; i++) {
        int r = rb + i * 16;
        As[kk][r] = ((const float*)A)[(row0 + r) * 256 + k0 + kk];
      }
    }
    {
      int kk = tid & 15;
      int nb = tid >> 4;
#pragma unroll
      for (int i = 0; i < 4; i++) {
        int n = nb + i * 16;
        Bs[kk][n] = ldg_f(Bw, (col0 + n) * 256 + k0 + kk, bf);
      }
    }
    __syncthreads();
#pragma unroll
    for (int kk = 0; kk < 16; kk++) {
      float4 a = *(const float4*)&As[kk][ty * 4];
      float4 b = *(const float4*)&Bs[kk][tx * 4];
      acc[0][0] += a.x * b.x; acc[0][1] += a.x * b.y; acc[0][2] += a.x * b.z; acc[0][3] += a.x * b.w;
      acc[1][0] += a.y * b.x; acc[1][1] += a.y * b.y; acc[1][2] += a.y * b.z; acc[1][3] += a.y * b.w;
      acc[2][0] += a.z * b.x; acc[2][1] += a.z * b.y; acc[2][2] += a.z * b.z; acc[2][3] += a.z * b.w;
      acc[3][0] += a.w * b.x; acc[3][1] += a.w * b.y; acc[3][2] += a.w * b.z; acc[3][3] += a.w * b.w;
    }
    __syncthreads();
  }
#pragma unroll
  for (int i = 0; i < 4; i++) {
    int r = row0 + ty * 4 + i;
    float4 v;
    v.x = acc[i][0] + ldg_f(bias, col0 + tx * 4 + 0, bf);
    v.y = acc[i][1] + ldg_f(bias, col0 + tx * 4 + 1, bf);
    v.z = acc[i][2] + ldg_f(bias, col0 + tx * 4 + 2, bf);
    v.w = acc[i][3] + ldg_f(bias, col0 + tx * 4 + 3, bf);
    *(float4*)&Cout[r * 256 + col0 + tx * 4] = v;
  }
}

// ---------------- offsets: dw-conv + LN + GELU + proj + ref + clip ----------------
__global__ __launch_bounds__(64) void k_offsets(const float* q_rm, const void* w_dw, const void* b_dw,
                                                const void* ln_g, const void* ln_b, const void* w_proj,
                                                float* pos, const int* flag) {
  int bid = blockIdx.x;           // g*36 + nn
  int g = bid / 36, nn = bid % 36;
  int b = g >> 3, nh = g & 7;
  int tk = nn / 9, hk = (nn / 3) % 3, wk = nn % 3;
  int lane = threadIdx.x;
  int ch = lane & 31, half = lane >> 5;
  int bf = flag[0];
  float sum = 0.f;
  for (int tap = half; tap < 243; tap += 2) {
    int dt = tap / 81, rem = tap % 81, dh = rem / 9, dw = rem % 9;
    int t = tk * 2 - 1 + dt, h = hk * 8 - 4 + dh, w = wk * 8 - 4 + dw;
    if (t < 0 || t >= 8 || h < 0 || h >= 24 || w < 0 || w >= 24) continue;
    float qv = q_rm[((b * 8 + t) * 576 + h * 24 + w) * 256 + nh * 32 + ch];
    float wv = ldg_f(w_dw, ((ch * 3 + dt) * 9 + dh) * 9 + dw, bf);
    sum += qv * wv;
  }
  sum += __shfl_xor(sum, 32);
  float v = sum + ldg_f(b_dw, ch, bf);
  float s1 = v;
  for (int m = 16; m; m >>= 1) s1 += __shfl_xor(s1, m);
  float mu = s1 * (1.f / 32.f);
  float d = v - mu;
  float s2 = d * d;
  for (int m = 16; m; m >>= 1) s2 += __shfl_xor(s2, m);
  float o = d * rsqrtf(s2 * (1.f / 32.f) + 1e-5f) * ldg_f(ln_g, ch, bf) + ldg_f(ln_b, ch, bf);
  o = 0.5f * o * (1.f + erff(o * 0.70710678118654752f));
  float res[3];
#pragma unroll
  for (int p = 0; p < 3; p++) {
    float t3 = o * ldg_f(w_proj, p * 32 + ch, bf);
    for (int m = 16; m; m >>= 1) t3 += __shfl_xor(t3, m);
    res[p] = t3;
  }
  if (lane == 0) {
    float ref0 = ((tk + 0.5f) / 3.f) * 2.f - 1.f;
    float ref1 = ((hk + 0.5f) / 2.f) * 2.f - 1.f;
    float ref2 = ((wk + 0.5f) / 2.f) * 2.f - 1.f;
    pos[bid * 3 + 0] = fminf(1.f, fmaxf(-1.f, res[0] + ref0));
    pos[bid * 3 + 1] = fminf(1.f, fmaxf(-1.f, res[1] + ref1));
    pos[bid * 3 + 2] = fminf(1.f, fmaxf(-1.f, res[2] + ref2));
  }
}

// ---------------- trilinear sample of xc at pos ----------------
__global__ __launch_bounds__(256) void k_sample(const float* xc_rm, const float* pos, float* xs_rm) {
  int g = blockIdx.x;
  int b = g >> 3, nh = g & 7;
  int tid = threadIdx.x;
  int ch = tid & 31;
  int sub = tid >> 5;
  for (int it = 0; it < 5; it++) {
    int nn = it * 8 + sub;
    if (nn >= 36) continue;
    float p0 = pos[(g * 36 + nn) * 3 + 0];
    float p1 = pos[(g * 36 + nn) * 3 + 1];
    float p2 = pos[(g * 36 + nn) * 3 + 2];
    // faithful to reference: gx=pos_t -> W axis, gy=pos_x -> H axis, gz=pos_y -> T axis
    float ix = (p0 + 1.f) * 0.5f * 23.f;
    float iy = (p2 + 1.f) * 0.5f * 23.f;
    float iz = (p1 + 1.f) * 0.5f * 7.f;
    float x0f = floorf(ix), y0f = floorf(iy), z0f = floorf(iz);
    float fx = ix - x0f, fy = iy - y0f, fz = iz - z0f;
    int x0 = min(max((int)x0f, 0), 23), x1 = min(x0 + 1, 23);
    int y0 = min(max((int)y0f, 0), 23), y1 = min(y0 + 1, 23);
    int z0 = min(max((int)z0f, 0), 7),  z1 = min(z0 + 1, 7);
    int c = nh * 32 + ch;
#define AT(z, y, x) xc_rm[(((b * 8 + (z)) * 576 + (y) * 24 + (x)) * 256 + c)]
    float v =
      AT(z0, y0, x0) * (1.f - fz) * (1.f - fy) * (1.f - fx) + AT(z0, y0, x1) * (1.f - fz) * (1.f - fy) * fx +
      AT(z0, y1, x0) * (1.f - fz) * fy * (1.f - fx)         + AT(z0, y1, x1) * (1.f - fz) * fy * fx +
      AT(z1, y0, x0) * fz * (1.f - fy) * (1.f - fx)         + AT(z1, y0, x1) * fz * (1.f - fy) * fx +
      AT(z1, y1, x0) * fz * fy * (1.f - fx)                 + AT(z1, y1, x1) * fz * fy * fx;
#undef AT
    xs_rm[(b * 36 + nn) * 256 + c] = v;
  }
}

// ---------------- k/v 1x1 conv (72x256x256 GEMMs) ----------------
__global__ __launch_bounds__(256) void k_kv(const float* xs_rm, const void* w_k, const void* b_k,
                                            const void* w_v, const void* b_v,
                                            float* k_rm, float* v_rm, const int* flag) {
  int bx = blockIdx.x;            // sel*72 + row
  int sel = bx / 72, row = bx % 72;
  int col = threadIdx.x;
  int bf = flag[0];
  const void* w = sel ? w_v : w_k;
  const void* bb = sel ? b_v : b_k;
  __shared__ float a[256];
  a[col] = xs_rm[row * 256 + col];
  __syncthreads();
  float s = 0.f;
  for (int c = 0; c < 256; c++) s += a[c] * ldg_f(w, col * 256 + c, bf);
  float* outp = sel ? v_rm : k_rm;
  outp[row * 256 + col] = s + ldg_f(bb, col, bf);
}

// ---------------- attention: QK + log-CPB bias + softmax + PV ----------------
__global__ __launch_bounds__(256) void k_attn(const float* q_rm, const float* k_rm, const float* v_rm,
                                              const float* pos, const void* rpe_w1, const void* rpe_b1,
                                              const void* rpe_w2, void* outp, const int* flag) {
  __shared__ float ks[36][32];
  __shared__ float vs[36][32];
  __shared__ float poss[36][3];
  __shared__ float4 wab[32];
  __shared__ float w2s[32];
  __shared__ float lsm[256][37];
  int g = blockIdx.y, b = g >> 3, nh = g & 7;
  int tid = threadIdx.x;
  int bf = flag[0];
  for (int e = tid; e < 36 * 32; e += 256) {
    int nn = e >> 5, ch = e & 31;
    ks[nn][ch] = k_rm[(b * 36 + nn) * 256 + nh * 32 + ch];
    vs[nn][ch] = v_rm[(b * 36 + nn) * 256 + nh * 32 + ch];
  }
  if (tid < 32) {
    wab[tid] = make_float4(ldg_f(rpe_w1, tid * 3 + 0, bf), ldg_f(rpe_w1, tid * 3 + 1, bf),
                           ldg_f(rpe_w1, tid * 3 + 2, bf), ldg_f(rpe_b1, tid, bf));
    w2s[tid] = ldg_f(rpe_w2, tid, bf);
  }
  for (int e = tid; e < 36 * 3; e += 256) poss[e / 3][e % 3] = pos[g * 108 + e];
  __syncthreads();

  int mm = blockIdx.x * 256 + tid;
  int t = mm / 576, hw = mm % 576, hh = hw / 24, wwi = hw % 24;
  float qreg[32];
  const float4* qp = (const float4*)&q_rm[(b * 4608 + mm) * 256 + nh * 32];
#pragma unroll
  for (int i = 0; i < 8; i++) {
    float4 v4 = qp[i];
    qreg[i * 4 + 0] = v4.x; qreg[i * 4 + 1] = v4.y; qreg[i * 4 + 2] = v4.z; qreg[i * 4 + 3] = v4.w;
  }
  float qg0 = t * (2.f / 7.f) - 1.f;
  float qg1 = hh * (2.f / 23.f) - 1.f;
  float qg2 = wwi * (2.f / 23.f) - 1.f;
  const float scale = 0.17677669529663687f;
  float mx = -1e30f;
  for (int nn = 0; nn < 36; nn++) {
    float s = 0.f;
#pragma unroll
    for (int ch = 0; ch < 32; ch++) s += qreg[ch] * ks[nn][ch];
    float d0 = (qg0 - poss[nn][0]) * 4.f;
    float d1 = (qg1 - poss[nn][1]) * 4.f;
    float d2 = (qg2 - poss[nn][2]) * 4.f;
    d0 = copysignf(__log2f(fabsf(d0) + 1.f) * (1.f / 3.f), d0);
    d1 = copysignf(__log2f(fabsf(d1) + 1.f) * (1.f / 3.f), d1);
    d2 = copysignf(__log2f(fabsf(d2) + 1.f) * (1.f / 3.f), d2);
    float bias = 0.f;
#pragma unroll
    for (int h = 0; h < 32; h++) {
      float4 w = wab[h];
      float hb = fmaf(d0, w.x, fmaf(d1, w.y, fmaf(d2, w.z, w.w)));
      bias = fmaf(fmaxf(hb, 0.f), w2s[h], bias);
    }
    float L = fmaf(s, scale, bias);
    lsm[tid][nn] = L;
    mx = fmaxf(mx, L);
  }
  float se = 0.f;
  for (int nn = 0; nn < 36; nn++) {
    float e = __expf(lsm[tid][nn] - mx);
    lsm[tid][nn] = e;
    se += e;
  }
  float inv = 1.f / se;
  float acc[32] = {};
  for (int nn = 0; nn < 36; nn++) {
    float p = lsm[tid][nn] * inv;
#pragma unroll
    for (int ch = 0; ch < 32; ch++) acc[ch] += p * vs[nn][ch];
  }
  int obase = ((b * 8 + t) * 256 + nh * 32) * 576 + hw;
  if (bf) {
    __hip_bfloat16* o = (__hip_bfloat16*)outp;
#pragma unroll
    for (int ch = 0; ch < 32; ch++) o[obase + ch * 576] = __float2bfloat16(acc[ch]);
  } else {
    float* o = (float*)outp;
#pragma unroll
    for (int ch = 0; ch < 32; ch++) o[obase + ch * 576] = acc[ch];
  }
}

extern "C" void kernel_launch(void* const* d_in, const int* in_sizes, int n_in,
                              void* d_out, int out_size, void* d_ws, size_t ws_size,
                              hipStream_t stream) {
  const void* x        = d_in[0];
  const void* w_in     = d_in[1];
  const void* b_in     = d_in[2];
  const void* w_q      = d_in[3];
  const void* b_q      = d_in[4];
  const void* w_off_dw = d_in[5];
  const void* b_off_dw = d_in[6];
  const void* ln_g     = d_in[7];
  const void* ln_b     = d_in[8];
  const void* w_off_pj = d_in[9];
  const void* w_k      = d_in[10];
  const void* b_k      = d_in[11];
  const void* w_v      = d_in[12];
  const void* b_v      = d_in[13];
  const void* rpe_w1   = d_in[14];
  const void* rpe_b1   = d_in[15];
  const void* rpe_w2   = d_in[16];

  float* ws  = (float*)d_ws;
  float* xc  = ws + WS_XC;
  float* q   = ws + WS_Q;
  float* pos = ws + WS_POS;
  float* xs  = ws + WS_XS;
  float* krm = ws + WS_K;
  float* vrm = ws + WS_V;
  int* flag  = (int*)(ws + WS_FLAG);

  k_detect<<<1, 64, 0, stream>>>(x, flag);
  k_gemm<0><<<dim3(4, 144), 256, 0, stream>>>(x, w_in, b_in, xc, flag);
  k_gemm<1><<<dim3(4, 144), 256, 0, stream>>>(xc, w_q, b_q, q, flag);
  k_offsets<<<576, 64, 0, stream>>>(q, w_off_dw, b_off_dw, ln_g, ln_b, w_off_pj, pos, flag);
  k_sample<<<16, 256, 0, stream>>>(xc, pos, xs);
  k_kv<<<144, 256, 0, stream>>>(xs, w_k, b_k, w_v, b_v, krm, vrm, flag);
  k_attn<<<dim3(18, 16), 256, 0, stream>>>(q, krm, vrm, pos, rpe_w1, rpe_b1, rpe_w2, d_out, flag);
}

// Round 3
// 201.240 us; speedup vs baseline: 1.0263x; 1.0263x over previous
//
#include <hip/hip_runtime.h>
#include <hip/hip_bf16.h>

typedef unsigned short ushortT;

// workspace float offsets (total ~14.6 MB < R1-proven 19.1 MB)
#define WS_XC   0          // 9216*256 fp32
#define WS_QB   2359296    // 9216*256 bf16 (as 1179648 floats)
#define WS_POS  3538944    // 16*36*3
#define WS_K    3540736    // 72*256
#define WS_V    3559168    // 72*256
#define WS_WC   3577600    // 256*256
#define WS_B512 3643136    // 512
#define WS_FLAG 3643648

__device__ __forceinline__ float bf2f(ushortT u) {
  union { unsigned int i; float f; } c; c.i = ((unsigned int)u) << 16; return c.f;
}
__device__ __forceinline__ ushortT f2bf(float f) {
  union { float f; unsigned int i; } c; c.f = f;
  unsigned int lsb = (c.i >> 16) & 1;
  return (ushortT)((c.i + 0x7fff + lsb) >> 16);
}
__device__ __forceinline__ float ldg_f(const void* p, int i, int bf) {
  return bf ? bf2f(((const ushortT*)p)[i]) : ((const float*)p)[i];
}

// ---------------- dtype detection ----------------
__global__ void k_detect(const void* x, int* flagout) {
  int lane = threadIdx.x;
  const ushortT* u = (const ushortT*)x;
  int wild = 0;
  for (int i = lane; i < 512; i += 64) {
    ushortT s = u[i];
    int e = (s >> 7) & 0xFF;
    if (e != 0 && (e < 90 || e > 160)) wild++;
  }
  for (int off = 32; off; off >>= 1) wild += __shfl_down(wild, off);
  if (lane == 0) flagout[0] = (wild > 40) ? 0 : 1;  // 1 => bf16 I/O
}

// ---------------- Wc = Wq*Win, bias512 = [b_in | Wq*b_in + b_q] ----------------
__global__ __launch_bounds__(256) void k_wc(const void* w_in, const void* b_in, const void* w_q,
                                            const void* b_q, float* wc, float* bias512, const int* flag) {
  int o = blockIdx.x, tid = threadIdx.x, bf = flag[0];
  __shared__ float wq_s[256];
  __shared__ float red[256];
  wq_s[tid] = ldg_f(w_q, o * 256 + tid, bf);
  __syncthreads();
  float s = 0.f;
#pragma unroll 8
  for (int j = 0; j < 256; j++) s += wq_s[j] * ldg_f(w_in, j * 256 + tid, bf);
  wc[o * 256 + tid] = s;
  red[tid] = wq_s[tid] * ldg_f(b_in, tid, bf);
  __syncthreads();
  for (int m = 128; m; m >>= 1) {
    if (tid < m) red[tid] += red[tid + m];
    __syncthreads();
  }
  if (tid == 0) bias512[256 + o] = red[0] + ldg_f(b_q, o, bf);
  if (o == 0) bias512[tid] = ldg_f(b_in, tid, bf);
}

// ---------------- fused GEMM: [xc | q] = x * [Win^T | Wc^T] + bias512 ----------------
// M=9216 (b,t,hw), N=512, K=256. x layout (b,t,c,h,w): A[r][k] at (bt*256+k)*576+hw.
// xc out fp32 [9216][256]; q out bf16 [9216][256].
__global__ __launch_bounds__(256) void k_gemm2(const void* x, const void* w_in, const float* wc,
                                               const float* bias512, float* xc, ushortT* qb,
                                               const int* flag) {
  const int bf = flag[0];
  __shared__ float As[2][32][68];
  __shared__ float Bs[2][32][68];
  int tid = threadIdx.x;
  int tx = tid & 15, ty = tid >> 4;
  int bid = blockIdx.x;
  int colT = bid / 144, rowT = bid % 144;   // same rowT -> same XCD (144%8==0)
  int col0 = colT * 64;
  int row0 = rowT * 64;
  int bt = row0 / 576;                      // 576%64==0: tiles never cross bt
  int hw0 = row0 % 576;
  int ar = (tid & 15) * 4;   // A stage: r offset
  int ak = tid >> 4;         // A stage: kk base (0..15), two passes
  int bn = tid & 63;         // B stage: n
  int bk = (tid >> 6) * 8;   // B stage: kk base
  const int isW = (col0 < 256);
  const ushortT* xB = (const ushortT*)x;
  const float*   xF = (const float*)x;
  const ushortT* wB = (const ushortT*)w_in;
  const float*   wF = (const float*)w_in;

  float areg[8], breg[8];

  auto loadA = [&](int k0) {
#pragma unroll
    for (int p = 0; p < 2; p++) {
      int idx = (bt * 256 + k0 + ak + p * 16) * 576 + hw0 + ar;
      if (bf) {
        ushort4 u = *(const ushort4*)(xB + idx);
        areg[p * 4 + 0] = bf2f(u.x); areg[p * 4 + 1] = bf2f(u.y);
        areg[p * 4 + 2] = bf2f(u.z); areg[p * 4 + 3] = bf2f(u.w);
      } else {
        float4 f = *(const float4*)(xF + idx);
        areg[p * 4 + 0] = f.x; areg[p * 4 + 1] = f.y;
        areg[p * 4 + 2] = f.z; areg[p * 4 + 3] = f.w;
      }
    }
  };
  auto loadB = [&](int k0) {
    if (isW) {
      if (bf) {
        const ushortT* pp = wB + (col0 + bn) * 256 + k0 + bk;
        ushort4 u0 = *(const ushort4*)pp;
        ushort4 u1 = *(const ushort4*)(pp + 4);
        breg[0] = bf2f(u0.x); breg[1] = bf2f(u0.y); breg[2] = bf2f(u0.z); breg[3] = bf2f(u0.w);
        breg[4] = bf2f(u1.x); breg[5] = bf2f(u1.y); breg[6] = bf2f(u1.z); breg[7] = bf2f(u1.w);
      } else {
        const float* pp = wF + (col0 + bn) * 256 + k0 + bk;
        float4 f0 = *(const float4*)pp;
        float4 f1 = *(const float4*)(pp + 4);
        breg[0] = f0.x; breg[1] = f0.y; breg[2] = f0.z; breg[3] = f0.w;
        breg[4] = f1.x; breg[5] = f1.y; breg[6] = f1.z; breg[7] = f1.w;
      }
    } else {
      const float* pp = wc + (col0 - 256 + bn) * 256 + k0 + bk;
      float4 f0 = *(const float4*)pp;
      float4 f1 = *(const float4*)(pp + 4);
      breg[0] = f0.x; breg[1] = f0.y; breg[2] = f0.z; breg[3] = f0.w;
      breg[4] = f1.x; breg[5] = f1.y; breg[6] = f1.z; breg[7] = f1.w;
    }
  };
  auto storeAB = [&](int buf) {
#pragma unroll
    for (int p = 0; p < 2; p++)
      *(float4*)&As[buf][ak + p * 16][ar] =
          make_float4(areg[p * 4 + 0], areg[p * 4 + 1], areg[p * 4 + 2], areg[p * 4 + 3]);
#pragma unroll
    for (int j = 0; j < 8; j++) Bs[buf][bk + j][bn] = breg[j];
  };

  float acc[4][4] = {};
  loadA(0); loadB(0);
  storeAB(0);
  __syncthreads();
  for (int kt = 0; kt < 8; kt++) {
    int cur = kt & 1;
    if (kt < 7) { loadA((kt + 1) * 32); loadB((kt + 1) * 32); }
#pragma unroll
    for (int kk = 0; kk < 32; kk++) {
      float4 a = *(const float4*)&As[cur][kk][ty * 4];
      float4 b = *(const float4*)&Bs[cur][kk][tx * 4];
      acc[0][0] += a.x * b.x; acc[0][1] += a.x * b.y; acc[0][2] += a.x * b.z; acc[0][3] += a.x * b.w;
      acc[1][0] += a.y * b.x; acc[1][1] += a.y * b.y; acc[1][2] += a.y * b.z; acc[1][3] += a.y * b.w;
      acc[2][0] += a.z * b.x; acc[2][1] += a.z * b.y; acc[2][2] += a.z * b.z; acc[2][3] += a.z * b.w;
      acc[3][0] += a.w * b.x; acc[3][1] += a.w * b.y; acc[3][2] += a.w * b.z; acc[3][3] += a.w * b.w;
    }
    if (kt < 7) storeAB(cur ^ 1);
    __syncthreads();
  }
  int cb = col0 & 255;
#pragma unroll
  for (int i = 0; i < 4; i++) {
    int r = row0 + ty * 4 + i;
    float4 v;
    v.x = acc[i][0] + bias512[col0 + tx * 4 + 0];
    v.y = acc[i][1] + bias512[col0 + tx * 4 + 1];
    v.z = acc[i][2] + bias512[col0 + tx * 4 + 2];
    v.w = acc[i][3] + bias512[col0 + tx * 4 + 3];
    if (isW) {
      *(float4*)&xc[r * 256 + cb + tx * 4] = v;
    } else {
      ushort4 u = make_ushort4(f2bf(v.x), f2bf(v.y), f2bf(v.z), f2bf(v.w));
      *(ushort4*)&qb[r * 256 + cb + tx * 4] = u;
    }
  }
}

// ---------------- offsets: dw-conv + LN + GELU + proj + ref + clip ----------------
__global__ __launch_bounds__(64) void k_offsets(const ushortT* qb, const void* w_dw, const void* b_dw,
                                                const void* ln_g, const void* ln_b, const void* w_proj,
                                                float* pos, const int* flag) {
  int bid = blockIdx.x;           // g*36 + nn
  int g = bid / 36, nn = bid % 36;
  int b = g >> 3, nh = g & 7;
  int tk = nn / 9, hk = (nn / 3) % 3, wk = nn % 3;
  int lane = threadIdx.x;
  int ch = lane & 31, half = lane >> 5;
  int bf = flag[0];
  float sum = 0.f;
  for (int tap = half; tap < 243; tap += 2) {
    int dt = tap / 81, rem = tap % 81, dh = rem / 9, dw = rem % 9;
    int t = tk * 2 - 1 + dt, h = hk * 8 - 4 + dh, w = wk * 8 - 4 + dw;
    if (t < 0 || t >= 8 || h < 0 || h >= 24 || w < 0 || w >= 24) continue;
    float qv = bf2f(qb[((b * 8 + t) * 576 + h * 24 + w) * 256 + nh * 32 + ch]);
    float wv = ldg_f(w_dw, ((ch * 3 + dt) * 9 + dh) * 9 + dw, bf);
    sum += qv * wv;
  }
  sum += __shfl_xor(sum, 32);
  float v = sum + ldg_f(b_dw, ch, bf);
  float s1 = v;
  for (int m = 16; m; m >>= 1) s1 += __shfl_xor(s1, m);
  float mu = s1 * (1.f / 32.f);
  float d = v - mu;
  float s2 = d * d;
  for (int m = 16; m; m >>= 1) s2 += __shfl_xor(s2, m);
  float o = d * rsqrtf(s2 * (1.f / 32.f) + 1e-5f) * ldg_f(ln_g, ch, bf) + ldg_f(ln_b, ch, bf);
  o = 0.5f * o * (1.f + erff(o * 0.70710678118654752f));
  float res[3];
#pragma unroll
  for (int p = 0; p < 3; p++) {
    float t3 = o * ldg_f(w_proj, p * 32 + ch, bf);
    for (int m = 16; m; m >>= 1) t3 += __shfl_xor(t3, m);
    res[p] = t3;
  }
  if (lane == 0) {
    float ref0 = ((tk + 0.5f) / 3.f) * 2.f - 1.f;
    float ref1 = ((hk + 0.5f) / 2.f) * 2.f - 1.f;
    float ref2 = ((wk + 0.5f) / 2.f) * 2.f - 1.f;
    pos[bid * 3 + 0] = fminf(1.f, fmaxf(-1.f, res[0] + ref0));
    pos[bid * 3 + 1] = fminf(1.f, fmaxf(-1.f, res[1] + ref1));
    pos[bid * 3 + 2] = fminf(1.f, fmaxf(-1.f, res[2] + ref2));
  }
}

// ---------------- fused trilinear sample + k/v 1x1 conv ----------------
__global__ __launch_bounds__(256) void k_svkv(const float* xc_rm, const float* pos,
                                              const void* w_k, const void* b_k,
                                              const void* w_v, const void* b_v,
                                              float* k_rm, float* v_rm, const int* flag) {
  int row = blockIdx.x;           // b*36 + nn
  int b = row / 36, nn = row % 36;
  int tid = threadIdx.x;
  int bf = flag[0];
  __shared__ float a[256];
  {
    int nh = tid >> 5;
    int g = b * 8 + nh;
    float p0 = pos[(g * 36 + nn) * 3 + 0];
    float p1 = pos[(g * 36 + nn) * 3 + 1];
    float p2 = pos[(g * 36 + nn) * 3 + 2];
    // faithful: gx=pos_t -> W axis, gy=pos_x -> H axis, gz=pos_y -> T axis
    float ix = (p0 + 1.f) * 0.5f * 23.f;
    float iy = (p2 + 1.f) * 0.5f * 23.f;
    float iz = (p1 + 1.f) * 0.5f * 7.f;
    float x0f = floorf(ix), y0f = floorf(iy), z0f = floorf(iz);
    float fx = ix - x0f, fy = iy - y0f, fz = iz - z0f;
    int x0 = min(max((int)x0f, 0), 23), x1 = min(x0 + 1, 23);
    int y0 = min(max((int)y0f, 0), 23), y1 = min(y0 + 1, 23);
    int z0 = min(max((int)z0f, 0), 7),  z1 = min(z0 + 1, 7);
#define AT(z, y, x) xc_rm[(((b * 8 + (z)) * 576 + (y) * 24 + (x)) * 256 + tid)]
    a[tid] =
      AT(z0, y0, x0) * (1.f - fz) * (1.f - fy) * (1.f - fx) + AT(z0, y0, x1) * (1.f - fz) * (1.f - fy) * fx +
      AT(z0, y1, x0) * (1.f - fz) * fy * (1.f - fx)         + AT(z0, y1, x1) * (1.f - fz) * fy * fx +
      AT(z1, y0, x0) * fz * (1.f - fy) * (1.f - fx)         + AT(z1, y0, x1) * fz * (1.f - fy) * fx +
      AT(z1, y1, x0) * fz * fy * (1.f - fx)                 + AT(z1, y1, x1) * fz * fy * fx;
#undef AT
  }
  __syncthreads();
  float sk = 0.f, sv = 0.f;
  if (bf) {
    const ushortT* wk = (const ushortT*)w_k + tid * 256;
    const ushortT* wv = (const ushortT*)w_v + tid * 256;
#pragma unroll 4
    for (int c = 0; c < 256; c += 8) {
      ushort4 k0 = *(const ushort4*)(wk + c), k1 = *(const ushort4*)(wk + c + 4);
      ushort4 v0 = *(const ushort4*)(wv + c), v1 = *(const ushort4*)(wv + c + 4);
      sk += a[c+0]*bf2f(k0.x) + a[c+1]*bf2f(k0.y) + a[c+2]*bf2f(k0.z) + a[c+3]*bf2f(k0.w)
          + a[c+4]*bf2f(k1.x) + a[c+5]*bf2f(k1.y) + a[c+6]*bf2f(k1.z) + a[c+7]*bf2f(k1.w);
      sv += a[c+0]*bf2f(v0.x) + a[c+1]*bf2f(v0.y) + a[c+2]*bf2f(v0.z) + a[c+3]*bf2f(v0.w)
          + a[c+4]*bf2f(v1.x) + a[c+5]*bf2f(v1.y) + a[c+6]*bf2f(v1.z) + a[c+7]*bf2f(v1.w);
    }
  } else {
    const float* wk = (const float*)w_k + tid * 256;
    const float* wv = (const float*)w_v + tid * 256;
#pragma unroll 4
    for (int c = 0; c < 256; c += 4) {
      float4 k4 = *(const float4*)(wk + c);
      float4 v4 = *(const float4*)(wv + c);
      sk += a[c]*k4.x + a[c+1]*k4.y + a[c+2]*k4.z + a[c+3]*k4.w;
      sv += a[c]*v4.x + a[c+1]*v4.y + a[c+2]*v4.z + a[c+3]*v4.w;
    }
  }
  k_rm[row * 256 + tid] = sk + ldg_f(b_k, tid, bf);
  v_rm[row * 256 + tid] = sv + ldg_f(b_v, tid, bf);
}

// ---------------- attention: QK + log-CPB bias + softmax + PV ----------------
__global__ __launch_bounds__(256) void k_attn(const ushortT* qb, const float* k_rm, const float* v_rm,
                                              const float* pos, const void* rpe_w1, const void* rpe_b1,
                                              const void* rpe_w2, void* outp, const int* flag) {
  __shared__ float ks[36][32];
  __shared__ float vs[36][32];
  __shared__ float poss[36][4];
  __shared__ float4 wab[32];
  __shared__ float w2s[32];
  int g = blockIdx.y, b = g >> 3, nh = g & 7;
  int tid = threadIdx.x;
  int bf = flag[0];
  for (int e = tid; e < 36 * 32; e += 256) {
    int nn = e >> 5, ch = e & 31;
    ks[nn][ch] = k_rm[(b * 36 + nn) * 256 + nh * 32 + ch];
    vs[nn][ch] = v_rm[(b * 36 + nn) * 256 + nh * 32 + ch];
  }
  if (tid < 32) {
    wab[tid] = make_float4(ldg_f(rpe_w1, tid * 3 + 0, bf), ldg_f(rpe_w1, tid * 3 + 1, bf),
                           ldg_f(rpe_w1, tid * 3 + 2, bf), ldg_f(rpe_b1, tid, bf));
    w2s[tid] = ldg_f(rpe_w2, tid, bf);
  }
  if (tid < 108) poss[tid / 3][tid % 3] = pos[g * 108 + tid];
  __syncthreads();

  int mm = blockIdx.x * 256 + tid;
  int t = mm / 576, hw = mm % 576, hh = hw / 24, wwi = hw % 24;
  float qreg[32];
  const ushort4* qp = (const ushort4*)&qb[(b * 4608 + mm) * 256 + nh * 32];
#pragma unroll
  for (int i = 0; i < 8; i++) {
    ushort4 u = qp[i];
    qreg[i * 4 + 0] = bf2f(u.x); qreg[i * 4 + 1] = bf2f(u.y);
    qreg[i * 4 + 2] = bf2f(u.z); qreg[i * 4 + 3] = bf2f(u.w);
  }
  float qg0 = t * (2.f / 7.f) - 1.f;
  float qg1 = hh * (2.f / 23.f) - 1.f;
  float qg2 = wwi * (2.f / 23.f) - 1.f;
  const float scale = 0.17677669529663687f;
  float p[36];
  float mx = -1e30f;
#pragma unroll
  for (int nn = 0; nn < 36; nn++) {
    float s = 0.f;
#pragma unroll
    for (int ch = 0; ch < 32; ch++) s += qreg[ch] * ks[nn][ch];
    float d0 = (qg0 - poss[nn][0]) * 4.f;
    float d1 = (qg1 - poss[nn][1]) * 4.f;
    float d2 = (qg2 - poss[nn][2]) * 4.f;
    d0 = copysignf(__log2f(fabsf(d0) + 1.f) * (1.f / 3.f), d0);
    d1 = copysignf(__log2f(fabsf(d1) + 1.f) * (1.f / 3.f), d1);
    d2 = copysignf(__log2f(fabsf(d2) + 1.f) * (1.f / 3.f), d2);
    float bias = 0.f;
#pragma unroll
    for (int h = 0; h < 32; h++) {
      float4 w = wab[h];
      float hb = fmaf(d0, w.x, fmaf(d1, w.y, fmaf(d2, w.z, w.w)));
      bias = fmaf(fmaxf(hb, 0.f), w2s[h], bias);
    }
    float L = fmaf(s, scale, bias);
    p[nn] = L;
    mx = fmaxf(mx, L);
  }
  float se = 0.f;
#pragma unroll
  for (int nn = 0; nn < 36; nn++) {
    float e = __expf(p[nn] - mx);
    p[nn] = e;
    se += e;
  }
  float inv = 1.f / se;
  float acc[32] = {};
#pragma unroll
  for (int nn = 0; nn < 36; nn++) {
    float pr = p[nn] * inv;
#pragma unroll
    for (int ch = 0; ch < 32; ch++) acc[ch] += pr * vs[nn][ch];
  }
  int obase = ((b * 8 + t) * 256 + nh * 32) * 576 + hw;
  if (bf) {
    __hip_bfloat16* o = (__hip_bfloat16*)outp;
#pragma unroll
    for (int ch = 0; ch < 32; ch++) o[obase + ch * 576] = __float2bfloat16(acc[ch]);
  } else {
    float* o = (float*)outp;
#pragma unroll
    for (int ch = 0; ch < 32; ch++) o[obase + ch * 576] = acc[ch];
  }
}

extern "C" void kernel_launch(void* const* d_in, const int* in_sizes, int n_in,
                              void* d_out, int out_size, void* d_ws, size_t ws_size,
                              hipStream_t stream) {
  const void* x        = d_in[0];
  const void* w_in     = d_in[1];
  const void* b_in     = d_in[2];
  const void* w_q      = d_in[3];
  const void* b_q      = d_in[4];
  const void* w_off_dw = d_in[5];
  const void* b_off_dw = d_in[6];
  const void* ln_g     = d_in[7];
  const void* ln_b     = d_in[8];
  const void* w_off_pj = d_in[9];
  const void* w_k      = d_in[10];
  const void* b_k      = d_in[11];
  const void* w_v      = d_in[12];
  const void* b_v      = d_in[13];
  const void* rpe_w1   = d_in[14];
  const void* rpe_b1   = d_in[15];
  const void* rpe_w2   = d_in[16];

  float* ws    = (float*)d_ws;
  float* xc    = ws + WS_XC;
  ushortT* qb  = (ushortT*)(ws + WS_QB);
  float* pos   = ws + WS_POS;
  float* krm   = ws + WS_K;
  float* vrm   = ws + WS_V;
  float* wcb   = ws + WS_WC;
  float* b512  = ws + WS_B512;
  int* flag    = (int*)(ws + WS_FLAG);

  k_detect<<<1, 64, 0, stream>>>(x, flag);
  k_wc<<<256, 256, 0, stream>>>(w_in, b_in, w_q, b_q, wcb, b512, flag);
  k_gemm2<<<1152, 256, 0, stream>>>(x, w_in, wcb, b512, xc, qb, flag);
  k_offsets<<<576, 64, 0, stream>>>(qb, w_off_dw, b_off_dw, ln_g, ln_b, w_off_pj, pos, flag);
  k_svkv<<<72, 256, 0, stream>>>(xc, pos, w_k, b_k, w_v, b_v, krm, vrm, flag);
  k_attn<<<dim3(18, 16), 256, 0, stream>>>(qb, krm, vrm, pos, rpe_w1, rpe_b1, rpe_w2, d_out, flag);
}